// Round 7
// baseline (164.162 us; speedup 1.0000x reference)
//
#include <hip/hip_runtime.h>
#include <hip/hip_bf16.h>

// GAT layer: B=2, N=2048, C_IN=128, H=16, c=8.
// E(i,j) = exp(lrelu(lp_i+lc_j))*2^-12 = max(P1_i*Q1_j, P2_i*Q2_j) & adjmask (f16).
// Aggregation: mfma_f32_16x16x32_f16; B-operand = [h feats | ones buffer].
// Round 21: two-regime split.
//  prep_kernel: pure streaming pass. adj -> adj_out copy + byte-mask array in
//   attn's exact consume layout (per (b,it): uint4 {row m, row m+16} per
//   (ch, m*4+q), wave reads 1KB contiguous per chunk). 75MB @ ~6TB/s ~ 12us.
//  attn_kernel: NO LDS, NO barriers. Wave = head x 32 i-rows x full j;
//   denominator from ones-col -> direct out (no partials/combine). Streams:
//   masks 4-deep register prefetch (coalesced global), qI/hQ 2-deep
//   (broadcast, L2-hot). Latency hidden by ILP; no vmcnt-drain points.
//  5 rounds showed in-kernel LDS staging couples HBM latency to barriers.
// d_out = [out: B*N*128][adj copy: B*N*N]

#define B_   2
#define N_   2048
#define CIN_ 128
#define H_   16

typedef _Float16 h2  __attribute__((ext_vector_type(2)));
typedef _Float16 v8h __attribute__((ext_vector_type(8)));
typedef float    v4f __attribute__((ext_vector_type(4)));

#define SC6 0.015625f   // 2^-6

__device__ inline h2 pk_f16(float a, float b) {
  return __builtin_bit_cast(h2, __builtin_amdgcn_cvt_pkrtz(a, b));
}
__device__ inline unsigned as_u32(h2 v) { return __builtin_bit_cast(unsigned, v); }
__device__ inline h2 as_h2(unsigned u) { return __builtin_bit_cast(h2, u); }

// 4 adjacency floats (exactly 0.0/1.0) -> 4 mask bytes 0x00/0xFF, j0 in byte0.
__device__ inline unsigned mask4(float4 f) {
  unsigned r = (unsigned)f.x | ((unsigned)f.y << 8) |
               ((unsigned)f.z << 16) | ((unsigned)f.w << 24);
  return (r << 8) - r;   // per-byte 0x01 -> 0xFF
}

__global__ __launch_bounds__(128) void proj_kernel(
    const float* __restrict__ nf, const float* __restrict__ W,
    const float* __restrict__ bias, const float* __restrict__ a,
    unsigned* __restrict__ hQ, unsigned* __restrict__ qI,
    float* __restrict__ lpT, unsigned* __restrict__ ones) {
  const int row0 = blockIdx.x * 4;       // 4 consecutive rows (same batch)
  const int t    = threadIdx.x;          // output column 0..127
  if (blockIdx.x == 0) {                 // ones-buffer for B-operand cols 8..15
    ones[t] = 0x3C003C00u; ones[t + 128] = 0x3C003C00u;
    ones[t + 256] = 0x3C003C00u; ones[t + 384] = 0x3C003C00u;
  }
  __shared__ float sNf[4][CIN_];
  ((float4*)&sNf[0][0])[t] = ((const float4*)(nf + (long)row0 * CIN_))[t];
  __syncthreads();
  float acc[4];
  const float bv = bias[t];
#pragma unroll
  for (int r = 0; r < 4; ++r) acc[r] = bv;
#pragma unroll 8
  for (int k = 0; k < CIN_; ++k) {
    const float w = W[k * 128 + t];
#pragma unroll
    for (int r = 0; r < 4; ++r) acc[r] = fmaf(sNf[r][k], w, acc[r]);
  }
  const int h = t >> 3, kc = t & 7;
  const int b = row0 >> 11, n0 = row0 & (N_ - 1);
  const int bh = b * H_ + h;
  const int cdw = n0 >> 1;               // j-pair dword index (2-aligned)
  uint2 hv;
  hv.x = as_u32(pk_f16(acc[0], acc[1]));
  hv.y = as_u32(pk_f16(acc[2], acc[3]));
  *(uint2*)(hQ + ((long)(bh * 8 + kc)) * (N_ / 2) + cdw) = hv;

  const float ap = a[h * 16 + kc], ac = a[h * 16 + 8 + kc];
  float lpv[4], lcv[4];
#pragma unroll
  for (int r = 0; r < 4; ++r) {
    float x = acc[r] * ap, y = acc[r] * ac;
#pragma unroll
    for (int s = 1; s < 8; s <<= 1) {
      x += __shfl_xor(x, s);
      y += __shfl_xor(y, s);
    }
    lpv[r] = x; lcv[r] = y;
  }
  if (kc == 0) {
    float4 l0 = {lpv[0], lpv[1], lpv[2], lpv[3]};
    *(float4*)(lpT + (long)bh * N_ + n0) = l0;
    uint2 q1, q2;
    q1.x = as_u32(pk_f16(__expf(lcv[0]) * SC6, __expf(lcv[1]) * SC6));
    q1.y = as_u32(pk_f16(__expf(lcv[2]) * SC6, __expf(lcv[3]) * SC6));
    q2.x = as_u32(pk_f16(__expf(0.2f * lcv[0]) * SC6, __expf(0.2f * lcv[1]) * SC6));
    q2.y = as_u32(pk_f16(__expf(0.2f * lcv[2]) * SC6, __expf(0.2f * lcv[3]) * SC6));
    // interleave: chunk(16 pairs)=32dw: [q1 quad0|q2 quad0|...|q1 quad3|q2 quad3]
    const int addr = bh * 2048 + (cdw >> 4) * 32 + ((cdw >> 2) & 3) * 8;
    const int off  = cdw & 3;            // 0 or 2
    *(uint2*)(qI + addr + off)     = q1;
    *(uint2*)(qI + addr + 4 + off) = q2;
  }
}

// Streaming pass: adj -> {adj_out copy, byte-mask array}.
// Mask layout (uint2 units) per (b,it): idx = ch*128 + (m*4+q)*2 + u,
// covering row it*32 + u*16 + m, cols ch*32 + q*8 .. +7.
// Thread map: t = m*8 + q*2 + u  ->  mask writes are fully coalesced
// (128 x 8B = 1KB contiguous per block-iteration).
__global__ __launch_bounds__(128) void prep_kernel(
    const float* __restrict__ adj, float* __restrict__ adj_out,
    uint2* __restrict__ mks) {
  // same XCD swizzle form as attn: (b,it) stripes land on the same XCD L2.
  const int Lp  = (blockIdx.x & 7) * 64 + (blockIdx.x >> 3);
  const int b   = Lp >> 8, it = (Lp >> 2) & 63, qtr = Lp & 3;
  const int t   = threadIdx.x;
  const int u   = t & 1, q = (t >> 1) & 3, m = (t >> 3) & 15;
  const int row = it * 32 + u * 16 + m;
  const long rbase = ((long)(b * N_) + row) * N_;
  uint2* mb = mks + ((long)(b * 64 + it)) * 8192;
#pragma unroll 4
  for (int cc = 0; cc < 16; ++cc) {
    const int ch  = qtr * 16 + cc;
    const int col = ch * 32 + q * 8;
    const float4 fa = *(const float4*)(adj + rbase + col);
    const float4 fb = *(const float4*)(adj + rbase + col + 4);
    *(float4*)(adj_out + rbase + col)     = fa;
    *(float4*)(adj_out + rbase + col + 4) = fb;
    uint2 mv; mv.x = mask4(fa); mv.y = mask4(fb);
    mb[ch * 128 + (m * 4 + q) * 2 + u] = mv;
  }
}

__global__ __launch_bounds__(256, 2) void attn_kernel(
    const unsigned* __restrict__ hQ, const unsigned* __restrict__ qI,
    const float* __restrict__ lpT, const unsigned* __restrict__ ones,
    const uint4* __restrict__ mks, float* __restrict__ out) {
  // XCD-chunked swizzle (bijective, 512 % 8 == 0): 4 sibling head-blocks of
  // one (b,it) stripe are consecutive logical ids -> same XCD L2.
  const int L  = (blockIdx.x & 7) * 64 + (blockIdx.x >> 3);
  const int hg = L & 3, it = (L >> 2) & 63, b = L >> 8;
  const int i0 = it * 32;
  const int t = threadIdx.x, w = t >> 6, lane = t & 63;
  const int m = lane & 15, q = lane >> 4;
  const int h = hg * 4 + w, bh = b * H_ + h;

  // per-row parent factors (subtile 0: rows i0+m, subtile 1: rows i0+16+m)
  const float lpa = lpT[(long)bh * N_ + i0 + m];
  const float lpb = lpT[(long)bh * N_ + i0 + 16 + m];
  const float e1a = __expf(lpa) * SC6, e2a = __expf(0.2f * lpa) * SC6;
  const float e1b = __expf(lpb) * SC6, e2b = __expf(0.2f * lpb) * SC6;
  const h2 P1a = pk_f16(e1a, e1a), P2a = pk_f16(e2a, e2a);
  const h2 P1b = pk_f16(e1b, e1b), P2b = pk_f16(e2b, e2b);

  // streams
  const uint4* mp = mks + ((long)(b * 64 + it)) * 4096 + (m * 4 + q);
  const unsigned* qp = qI + bh * 2048 + q * 8;
  const unsigned hmask = (m < 8) ? ~0u : 0u;
  const unsigned* hp = (m < 8)
      ? hQ + ((long)(bh * 8 + m)) * (N_ / 2) + q * 4
      : ones + q * 4;

  // register prefetch: masks 4-deep, q 2-deep, hQ 2-deep
  uint4 bmk[4], bq1[2], bq2[2], bhq[2];
#pragma unroll
  for (int d = 0; d < 4; ++d) bmk[d] = mp[d * 64];
  bq1[0] = *(const uint4*)(qp);       bq2[0] = *(const uint4*)(qp + 4);
  bq1[1] = *(const uint4*)(qp + 32);  bq2[1] = *(const uint4*)(qp + 36);
  bhq[0] = *(const uint4*)(hp);
  bhq[1] = *(const uint4*)(hp + (16 & hmask));

  v4f acc0 = {0.f, 0.f, 0.f, 0.f};       // rows i0 .. i0+15
  v4f acc1 = {0.f, 0.f, 0.f, 0.f};       // rows i0+16 .. i0+31

  for (int t16 = 0; t16 < 4; ++t16) {
#pragma unroll
    for (int cc = 0; cc < 16; ++cc) {
      const int ch = t16 * 16 + cc;
      const int p2 = ch & 1, p4 = ch & 3;
      // prefetches (wrap keeps addresses in-bounds; overrun data discarded)
      const uint4 nmk = mp[((ch + 4) & 63) * 64];
      const int qn = ((ch + 2) & 63) * 32;
      const uint4 nq1 = *(const uint4*)(qp + qn);
      const uint4 nq2 = *(const uint4*)(qp + qn + 4);
      const uint4 nhq = *(const uint4*)(hp + ((((ch + 2) & 63) * 16) & hmask));

      const uint2 Mv0 = {bmk[p4].x, bmk[p4].y};   // row i0+m
      const uint2 Mv1 = {bmk[p4].z, bmk[p4].w};   // row i0+16+m
      const unsigned m0a = __builtin_amdgcn_perm(Mv0.x, Mv0.x, 0x01010000u);
      const unsigned m0b = __builtin_amdgcn_perm(Mv0.x, Mv0.x, 0x03030202u);
      const unsigned m0c = __builtin_amdgcn_perm(Mv0.y, Mv0.y, 0x01010000u);
      const unsigned m0d = __builtin_amdgcn_perm(Mv0.y, Mv0.y, 0x03030202u);
      const unsigned m1a = __builtin_amdgcn_perm(Mv1.x, Mv1.x, 0x01010000u);
      const unsigned m1b = __builtin_amdgcn_perm(Mv1.x, Mv1.x, 0x03030202u);
      const unsigned m1c = __builtin_amdgcn_perm(Mv1.y, Mv1.y, 0x01010000u);
      const unsigned m1d = __builtin_amdgcn_perm(Mv1.y, Mv1.y, 0x03030202u);

      const uint4 q1 = bq1[p2], q2 = bq2[p2];
      const h2 Q1x = as_h2(q1.x), Q1y = as_h2(q1.y), Q1z = as_h2(q1.z), Q1w = as_h2(q1.w);
      const h2 Q2x = as_h2(q2.x), Q2y = as_h2(q2.y), Q2z = as_h2(q2.z), Q2w = as_h2(q2.w);
      const v8h bf = __builtin_bit_cast(v8h, bhq[p2]);

      const uint4 af0 = {
        as_u32(__builtin_elementwise_max(P1a * Q1x, P2a * Q2x)) & m0a,
        as_u32(__builtin_elementwise_max(P1a * Q1y, P2a * Q2y)) & m0b,
        as_u32(__builtin_elementwise_max(P1a * Q1z, P2a * Q2z)) & m0c,
        as_u32(__builtin_elementwise_max(P1a * Q1w, P2a * Q2w)) & m0d};
      acc0 = __builtin_amdgcn_mfma_f32_16x16x32_f16(
          __builtin_bit_cast(v8h, af0), bf, acc0, 0, 0, 0);
      const uint4 af1 = {
        as_u32(__builtin_elementwise_max(P1b * Q1x, P2b * Q2x)) & m1a,
        as_u32(__builtin_elementwise_max(P1b * Q1y, P2b * Q2y)) & m1b,
        as_u32(__builtin_elementwise_max(P1b * Q1z, P2b * Q2z)) & m1c,
        as_u32(__builtin_elementwise_max(P1b * Q1w, P2b * Q2w)) & m1d};
      acc1 = __builtin_amdgcn_mfma_f32_16x16x32_f16(
          __builtin_bit_cast(v8h, af1), bf, acc1, 0, 0, 0);

      bmk[p4] = nmk; bq1[p2] = nq1; bq2[p2] = nq2; bhq[p2] = nhq;
    }
  }

  // D: col = m, row = q*4 + r. Denominator in col 8 (ones-columns).
#pragma unroll
  for (int u = 0; u < 2; ++u) {
    const v4f av = u ? acc1 : acc0;
#pragma unroll
    for (int r = 0; r < 4; ++r) {
      const float sden = __shfl(av[r], (lane & 48) | 8);
      if (m < 8) {
        const long gi = ((long)(b * N_ + i0 + u * 16 + q * 4 + r)) * H_ + h;
        out[gi * 8 + m] = av[r] / sden;
      }
    }
  }
}

extern "C" void kernel_launch(void* const* d_in, const int* in_sizes, int n_in,
                              void* d_out, int out_size, void* d_ws, size_t ws_size,
                              hipStream_t stream) {
  const float* nf   = (const float*)d_in[0];
  const float* adj  = (const float*)d_in[1];
  const float* W    = (const float*)d_in[2];
  const float* bias = (const float*)d_in[3];
  const float* a    = (const float*)d_in[4];

  float* out     = (float*)d_out;
  float* adj_out = out + (long)B_ * N_ * H_ * 8;    // 524288 offset

  unsigned* ws   = (unsigned*)d_ws;
  unsigned* hQ   = ws;                       // 262144 dw
  unsigned* qI   = ws + 262144;              // 65536 dw
  float*    lpT  = (float*)(ws + 327680);    // 65536 floats
  unsigned* ones = ws + 393216;              // 512 dw
  unsigned* mks  = ws + 393728;              // 2097152 dw (8 MB)

  hipLaunchKernelGGL(proj_kernel, dim3(B_ * N_ / 4), dim3(128), 0, stream,
                     nf, W, bias, a, hQ, qI, lpT, ones);
  hipLaunchKernelGGL(prep_kernel, dim3(512), dim3(128), 0, stream,
                     adj, adj_out, (uint2*)mks);
  hipLaunchKernelGGL(attn_kernel, dim3(512), dim3(256), 0, stream,
                     hQ, qI, lpT, ones, (const uint4*)mks, out);
}